// Round 3
// baseline (126.094 us; speedup 1.0000x reference)
//
#include <hip/hip_runtime.h>
#include <cstddef>

#define BB 16
#define PP 4
#define HH 32
#define WW 32
#define DD 32
#define CC 8

#define NBLK   2048      // 8 blocks/CU available; 64 slices x 32 h-rows
#define ITERS  8         // h-row (1024 voxels) = 8 iters x 128 voxels
#define VPI    128       // voxels per iter (256 threads, 2 halves/voxel)

typedef float fx4 __attribute__((ext_vector_type(4)));

// R7: persistent blocks + software pipeline + XCD-chunked swizzle + packed lanes.
// Evidence driving this: R0 (packed loads, 2x VALU) and R6 (half VALU, split
// lines) both sit at ~43-45us / 3.2 TB/s / VALUBusy<=15% / Occ 53% -> nothing
// saturated => latency/queue-continuity bound, not VALU or line-throughput.
// Changes:
//  * lanes 2k/2k+1 = halves of voxel k  -> every corner load is a fully
//    packed contiguous 1KB (16 lines) per instruction (R0's proven layout)
//  * each block owns one full h-row (1024 voxels) of one (b,p) slice,
//    processed as 8 double-buffered iterations: issue loads for iter j+1,
//    then consume iter j -> waves keep 8-16 loads in flight continuously
//    instead of burst-16/drain-0/die
//  * XCD swizzle: block b -> chunk (b&7)*256 + (b>>3); each XCD covers 8
//    contiguous slices and walks h sequentially -> corner overlap (x = h+-6)
//    hits the local L2; HBM sees 8 near-sequential streams
//  * j-invariant coordinate math hoisted (only w varies across iters)
__global__ __launch_bounds__(256, 4) void resample_kernel(
    const float* __restrict__ fmap,
    const float* __restrict__ theta,
    float* __restrict__ out)
{
    const int tid  = threadIdx.x;
    const int half = tid & 1;                 // which fx4 of the 8 channels
    const int vt   = tid >> 1;                // voxel-within-iter 0..127

    // bijective XCD-chunked swizzle (NBLK % 8 == 0)
    const int chunk = (blockIdx.x & 7) * (NBLK / 8) + (blockIdx.x >> 3);
    const int vox0  = chunk * (ITERS * VPI);  // h-row base, 1024-aligned

    const int bp = vox0 >> 15;                // uniform per block -> s_load theta
    const int h  = (vox0 & 32767) >> 10;      // constant per block
    const int d  = vt & 31;                   // constant per thread
    const int wb = vt >> 5;                   // w = j*4 + wb

    const float* th = theta + bp * 12;
    const float t0 = th[0], t1 = th[1], t2  = th[2],  t3  = th[3];
    const float t4 = th[4], t5 = th[5], t6  = th[6],  t7  = th[7];
    const float t8 = th[8], t9 = th[9], t10 = th[10], t11 = th[11];

    const float fh = (float)h, fd = (float)d;
    // j-invariant inner FMA chains (+2 pad folded in)
    const float xb = fmaf(t1, fh, fmaf(t2,  fd, t3 )) + 2.0f;
    const float yb = fmaf(t5, fh, fmaf(t6,  fd, t7 )) + 2.0f;
    const float zb = fmaf(t9, fh, fmaf(t10, fd, t11)) + 2.0f;

    const float* __restrict__ base =
        fmap + (size_t)bp * (HH * WW * DD * CC) + half * 4;

    // ---- per-iteration address/weight math (identical semantics to R6) ----
    auto compute = [&](int j, unsigned* voff, float* wgt) {
        const float fw = (float)(j * 4 + wb);
        const float x = fmaf(t0, fw, xb);
        const float y = fmaf(t4, fw, yb);
        const float z = fmaf(t8, fw, zb);

        const int x0 = min(max((int)floorf(x), 0), HH + 2);
        const int y0 = min(max((int)floorf(y), 0), HH + 2);
        const int z0 = min(max((int)floorf(z), 0), HH + 2);
        const float xd = x - (float)x0, yd = y - (float)y0, zd = z - (float)z0;

        const int ix[2] = { x0 - 2, x0 - 1 };  // x indexes the H axis (ref quirk)
        const int iy[2] = { y0 - 2, y0 - 1 };
        const int iz[2] = { z0 - 2, z0 - 1 };
        const float wxv[2] = { (1.0f - xd) * (((unsigned)ix[0] < (unsigned)HH) ? 1.0f : 0.0f),
                               xd          * (((unsigned)ix[1] < (unsigned)HH) ? 1.0f : 0.0f) };
        const float wyv[2] = { (1.0f - yd) * (((unsigned)iy[0] < (unsigned)WW) ? 1.0f : 0.0f),
                               yd          * (((unsigned)iy[1] < (unsigned)WW) ? 1.0f : 0.0f) };
        const float wzv[2] = { (1.0f - zd) * (((unsigned)iz[0] < (unsigned)DD) ? 1.0f : 0.0f),
                               zd          * (((unsigned)iz[1] < (unsigned)DD) ? 1.0f : 0.0f) };
        const unsigned ox[2] = { (unsigned)(min(max(ix[0], 0), HH - 1) * (WW * DD * CC)),
                                 (unsigned)(min(max(ix[1], 0), HH - 1) * (WW * DD * CC)) };
        const unsigned oy[2] = { (unsigned)(min(max(iy[0], 0), WW - 1) * (DD * CC)),
                                 (unsigned)(min(max(iy[1], 0), WW - 1) * (DD * CC)) };
        const unsigned oz[2] = { (unsigned)(min(max(iz[0], 0), DD - 1) * CC),
                                 (unsigned)(min(max(iz[1], 0), DD - 1) * CC) };
        #pragma unroll
        for (int i = 0; i < 8; ++i) {
            const int bx = (i >> 2) & 1, by = (i >> 1) & 1, bz = i & 1;
            voff[i] = ox[bx] + oy[by] + oz[bz];
            wgt[i]  = wxv[bx] * wyv[by] * wzv[bz];
        }
    };

    auto issue = [&](const unsigned* voff, fx4* c) {
        #pragma unroll
        for (int i = 0; i < 8; ++i)
            c[i] = *(const fx4*)(base + voff[i]);   // packed: 64 lanes = 1KB contiguous
    };

    auto consume_store = [&](int j, const float* wgt, const fx4* c) {
        fx4 acc = (fx4){0.f, 0.f, 0.f, 0.f};
        #pragma unroll
        for (int i = 0; i < 8; ++i) {
            acc.x = fmaf(wgt[i], c[i].x, acc.x);
            acc.y = fmaf(wgt[i], c[i].y, acc.y);
            acc.z = fmaf(wgt[i], c[i].z, acc.z);
            acc.w = fmaf(wgt[i], c[i].w, acc.w);
        }
        float* o = out + (size_t)(vox0 + j * VPI + vt) * CC + half * 4;
        __builtin_nontemporal_store(acc, (fx4*)o);  // wave = 1KB contiguous
    };

    // ---- double-buffered pipeline: issue j+1, consume j ----
    unsigned voff[8];
    float wgtA[8], wgtB[8];
    fx4 cA[8], cB[8];

    compute(0, voff, wgtA);
    issue(voff, cA);

    #pragma unroll
    for (int jj = 0; jj < ITERS; jj += 2) {
        if (jj + 1 < ITERS) { compute(jj + 1, voff, wgtB); issue(voff, cB); }
        __builtin_amdgcn_sched_barrier(0);   // keep B's issue ahead of A's drain
        consume_store(jj, wgtA, cA);
        if (jj + 2 < ITERS) { compute(jj + 2, voff, wgtA); issue(voff, cA); }
        __builtin_amdgcn_sched_barrier(0);
        consume_store(jj + 1, wgtB, cB);
    }
}

extern "C" void kernel_launch(void* const* d_in, const int* in_sizes, int n_in,
                              void* d_out, int out_size, void* d_ws, size_t ws_size,
                              hipStream_t stream) {
    const float* fmap  = (const float*)d_in[0];
    const float* theta = (const float*)d_in[1];
    float* out = (float*)d_out;

    resample_kernel<<<dim3(NBLK), dim3(256), 0, stream>>>(fmap, theta, out);
}

// Round 4
// 123.695 us; speedup vs baseline: 1.0194x; 1.0194x over previous
//
#include <hip/hip_runtime.h>
#include <cstddef>

#define BB 16
#define PP 4
#define HH 32
#define WW 32
#define DD 32
#define CC 8

typedef float fx4 __attribute__((ext_vector_type(4)));

// R8: z-corner shuffle-sharing. Evidence: R0/R6/R7 (three different schedules)
// all pinned at ~45us with HBM<=40%, VALU<=23%, Occ<=53% -> hidden saturated
// pipe = per-CU vector-memory gather address processing (per-lane). Fix:
// voxel d's z1-corner fx4 == voxel d+1's z0-corner fx4 whenever the neighbor's
// (x0,y0,z0) == mine + (0,0,1). Lanes are d-adjacent in this layout, so pull
// the z1 data over the DS pipe (__shfl lane+1, parallel to TA) and only load
// it when the index-step check fails (~15% of lanes, exec-masked loads).
// Exactness: predicate compares the neighbor's ACTUAL packed indices
// (shuffled), so shared data is bit-identical to a direct load.
__global__ __launch_bounds__(256, 4) void resample_kernel(
    const float* __restrict__ fmap,
    const float* __restrict__ theta,
    float* __restrict__ out)
{
    const int g    = blockIdx.x * 256 + threadIdx.x;  // global voxel id
    const int lane = threadIdx.x & 63;
    const int bp   = g >> 15;                         // (b,p): 32768 voxels each
    const int r    = g & 32767;
    const int h    = r >> 10;
    const int w    = (r >> 5) & 31;
    const int d    = r & 31;                          // lanes 0..31 / 32..63 are d=0..31

    const float* th = theta + bp * 12;                // uniform -> s_load
    const float t0 = th[0], t1 = th[1], t2  = th[2],  t3  = th[3];
    const float t4 = th[4], t5 = th[5], t6  = th[6],  t7  = th[7];
    const float t8 = th[8], t9 = th[9], t10 = th[10], t11 = th[11];

    const float fw = (float)w, fh = (float)h, fd = (float)d;
    const float x = fmaf(t0, fw, fmaf(t1, fh, fmaf(t2,  fd, t3 ))) + 2.0f;
    const float y = fmaf(t4, fw, fmaf(t5, fh, fmaf(t6,  fd, t7 ))) + 2.0f;
    const float z = fmaf(t8, fw, fmaf(t9, fh, fmaf(t10, fd, t11))) + 2.0f;

    // faithful: floor -> clip to [0, H+2] in padded coords (all axes H+2)
    const int x0 = min(max((int)floorf(x), 0), HH + 2);
    const int y0 = min(max((int)floorf(y), 0), HH + 2);
    const int z0 = min(max((int)floorf(z), 0), HH + 2);
    const float xd = x - (float)x0, yd = y - (float)y0, zd = z - (float)z0;

    const int ix[2] = { x0 - 2, x0 - 1 };             // x indexes the H axis (ref quirk)
    const int iy[2] = { y0 - 2, y0 - 1 };
    const int iz[2] = { z0 - 2, z0 - 1 };
    const float wxv[2] = { (1.0f - xd) * (((unsigned)ix[0] < (unsigned)HH) ? 1.0f : 0.0f),
                           xd          * (((unsigned)ix[1] < (unsigned)HH) ? 1.0f : 0.0f) };
    const float wyv[2] = { (1.0f - yd) * (((unsigned)iy[0] < (unsigned)WW) ? 1.0f : 0.0f),
                           yd          * (((unsigned)iy[1] < (unsigned)WW) ? 1.0f : 0.0f) };
    const float wzv[2] = { (1.0f - zd) * (((unsigned)iz[0] < (unsigned)DD) ? 1.0f : 0.0f),
                           zd          * (((unsigned)iz[1] < (unsigned)DD) ? 1.0f : 0.0f) };
    const unsigned ox[2] = { (unsigned)(min(max(ix[0], 0), HH - 1) * (WW * DD * CC)),
                             (unsigned)(min(max(ix[1], 0), HH - 1) * (WW * DD * CC)) };
    const unsigned oy[2] = { (unsigned)(min(max(iy[0], 0), WW - 1) * (DD * CC)),
                             (unsigned)(min(max(iy[1], 0), WW - 1) * (DD * CC)) };
    const unsigned ozA = (unsigned)(min(max(iz[0], 0), DD - 1) * CC);
    const unsigned ozB = (unsigned)(min(max(iz[1], 0), DD - 1) * CC);

    const float* __restrict__ base = fmap + (size_t)bp * (HH * WW * DD * CC);

    // ---- sharing predicate: neighbor lane (+1, same w since d<31) has
    // (x0,y0,z0) exactly one z-step ahead -> its z0-corner loads are
    // bit-identical to my z1-corner needs (same clamp, same address).
    const int pack    = (x0 << 12) | (y0 << 6) | z0;  // fields fit: 0..34
    const int nb_pack = __shfl(pack, lane + 1, 64);   // lane 63 wraps; masked below
    const bool share  = (d != 31) && (nb_pack == pack + 1);

    // ---- load phase: 8 z0-loads always; 8 z1-loads only where sharing fails.
    unsigned pxy[4];
    fx4 Alo[4], Ahi[4], Blo[4], Bhi[4];
    #pragma unroll
    for (int i = 0; i < 4; ++i) {
        const int bx = i >> 1, by = i & 1;
        pxy[i] = ox[bx] + oy[by];
        Alo[i] = *(const fx4*)(base + pxy[i] + ozA);
        Ahi[i] = *(const fx4*)(base + pxy[i] + ozA + 4);
    }
    if (!share) {                                     // exec-masked, ~15% lanes
        #pragma unroll
        for (int i = 0; i < 4; ++i) {
            Blo[i] = *(const fx4*)(base + pxy[i] + ozB);
            Bhi[i] = *(const fx4*)(base + pxy[i] + ozB + 4);
        }
    }
    __builtin_amdgcn_sched_barrier(0);                // keep the batch issued

    // ---- consume: z1 data via DS shuffle when shared, else fallback load.
    fx4 alo = (fx4){0.f, 0.f, 0.f, 0.f};
    fx4 ahi = (fx4){0.f, 0.f, 0.f, 0.f};
    #pragma unroll
    for (int i = 0; i < 4; ++i) {
        const int bx = i >> 1, by = i & 1;
        const float wxy = wxv[bx] * wyv[by];
        const float wA = wxy * wzv[0];
        const float wB = wxy * wzv[1];

        fx4 slo, shi;
        #pragma unroll
        for (int c = 0; c < 4; ++c) {
            slo[c] = __shfl(Alo[i][c], lane + 1, 64); // neighbor's z0 == my z1
            shi[c] = __shfl(Ahi[i][c], lane + 1, 64);
        }
        #pragma unroll
        for (int c = 0; c < 4; ++c) {
            const float blo = share ? slo[c] : Blo[i][c];
            const float bhi = share ? shi[c] : Bhi[i][c];
            alo[c] = fmaf(wA, Alo[i][c], fmaf(wB, blo, alo[c]));
            ahi[c] = fmaf(wA, Ahi[i][c], fmaf(wB, bhi, ahi[c]));
        }
    }

    // g enumerates voxels in output order -> coalesced 2KB/wave stores
    float* o = out + (size_t)g * CC;
    __builtin_nontemporal_store(alo, (fx4*)o);
    __builtin_nontemporal_store(ahi, (fx4*)(o + 4));
}

extern "C" void kernel_launch(void* const* d_in, const int* in_sizes, int n_in,
                              void* d_out, int out_size, void* d_ws, size_t ws_size,
                              hipStream_t stream) {
    const float* fmap  = (const float*)d_in[0];
    const float* theta = (const float*)d_in[1];
    float* out = (float*)d_out;

    const int total_blocks = (BB * PP * HH * WW * DD) / 256;  // 8192
    resample_kernel<<<dim3(total_blocks), dim3(256), 0, stream>>>(fmap, theta, out);
}